// Round 3
// baseline (128.266 us; speedup 1.0000x reference)
//
#include <hip/hip_runtime.h>
#include <math.h>

#define BATCH 64
#define TLEN 2048
#define DIM 80
#define DO8 (DIM / 8)         // 10 oct-chunks per row
#define TT 8                  // t-rows per thread strip
#define TCHUNKS (TLEN / TT)   // 256
#define THREADS 256
#define NSTRIPS (BATCH * TCHUNKS * DO8)       // 163840 threads
#define NBLOCKS (NSTRIPS / THREADS)           // 640

// Smooth-min: K=32; c = K*log2(e)
#define SMIN_C  46.166241308446828f
#define SMIN_RC 0.02166084939249829f   // 1/c

__device__ __forceinline__ void load_row8(float r[10], const float* __restrict__ base,
                                          int t, int q8) {
    // base -> tgt[b][0][d0]; r[0]=d0-1, r[1..8]=d0..d0+7, r[9]=d0+8
    if (t >= 0 && t < TLEN) {
        const float* p = base + (size_t)t * DIM;
        const float4 a = *(const float4*)p;
        const float4 c = *(const float4*)(p + 4);
        r[0] = (q8 > 0)       ? p[-1] : 0.f;
        r[1] = a.x; r[2] = a.y; r[3] = a.z; r[4] = a.w;
        r[5] = c.x; r[6] = c.y; r[7] = c.z; r[8] = c.w;
        r[9] = (q8 < DO8 - 1) ? p[8]  : 0.f;
    } else {
#pragma unroll
        for (int i = 0; i < 10; ++i) r[i] = 0.f;
    }
}

__device__ __forceinline__ float elem_loss(float x, const float* rm, const float* r0,
                                           const float* rp, int e) {
    float v[9];
#pragma unroll
    for (int i = 0; i < 3; ++i) {
        v[0 + i] = fabsf(x - rm[e + i]);
        v[3 + i] = fabsf(x - r0[e + i]);
        v[6 + i] = fabsf(x - rp[e + i]);
    }
    const float center = v[4];
    float m = fminf(fminf(fminf(v[0], v[1]), fminf(v[2], v[3])),
                    fminf(fminf(v[4], v[5]), fminf(v[6], v[7])));
    m = fminf(m, v[8]);
    const float cm = SMIN_C * m;
    float S = 0.f;
#pragma unroll
    for (int s = 0; s < 9; ++s)
        S += __builtin_amdgcn_exp2f(fmaf(-SMIN_C, v[s], cm));  // args <= 0; S in [1,9]
    const float sm = m - __builtin_amdgcn_logf(S) * SMIN_RC;    // logf builtin = log2
    return center + sm;
}

__global__ __launch_bounds__(THREADS) void jitter_kernel(
    const float* __restrict__ inp, const float* __restrict__ tgt,
    float* __restrict__ ws, float* __restrict__ out)
{
    __shared__ float wsum[THREADS / 64];

    const int n   = blockIdx.x * THREADS + threadIdx.x;
    const int q8  = n % DO8;
    const int rem = n / DO8;
    const int tc  = rem % TCHUNKS;
    const int b   = rem / TCHUNKS;
    const int t0  = tc * TT;
    const int d0  = q8 * 8;

    const float* tgb = tgt + (size_t)b * TLEN * DIM + d0;
    const float* inb = inp + (size_t)b * TLEN * DIM + d0;

    float rm[10], r0[10], rp[10];
    load_row8(rm, tgb, t0 - 1, q8);
    load_row8(r0, tgb, t0,     q8);

    float acc = 0.f;
#pragma unroll
    for (int lt = 0; lt < TT; ++lt) {
        load_row8(rp, tgb, t0 + lt + 1, q8);
        const float* ip = inb + (size_t)(t0 + lt) * DIM;
        const float4 ia = *(const float4*)ip;
        const float4 ic = *(const float4*)(ip + 4);
        acc += elem_loss(ia.x, rm, r0, rp, 0);
        acc += elem_loss(ia.y, rm, r0, rp, 1);
        acc += elem_loss(ia.z, rm, r0, rp, 2);
        acc += elem_loss(ia.w, rm, r0, rp, 3);
        acc += elem_loss(ic.x, rm, r0, rp, 4);
        acc += elem_loss(ic.y, rm, r0, rp, 5);
        acc += elem_loss(ic.z, rm, r0, rp, 6);
        acc += elem_loss(ic.w, rm, r0, rp, 7);
#pragma unroll
        for (int i = 0; i < 10; ++i) { rm[i] = r0[i]; r0[i] = rp[i]; }
    }

    // block reduction
#pragma unroll
    for (int off = 32; off > 0; off >>= 1)
        acc += __shfl_down(acc, off, 64);
    const int lane = threadIdx.x & 63, wid = threadIdx.x >> 6;
    if (lane == 0) wsum[wid] = acc;
    __syncthreads();
    if (threadIdx.x == 0) {
        float tot = 0.f;
#pragma unroll
        for (int w = 0; w < THREADS / 64; ++w) tot += wsum[w];
        // device-scope accumulate + last-block finalize (ws[0]=sum, ws_int[1]=count)
        atomicAdd(&ws[0], tot);
        __threadfence();
        int old = atomicAdd((int*)ws + 1, 1);
        if (old == NBLOCKS - 1) {
            __threadfence();
            const float s = atomicAdd(&ws[0], 0.f);  // coherent read of final sum
            out[0] = s * (0.5f / (float)((size_t)BATCH * TLEN * DIM));
        }
    }
}

__global__ void zero_kernel(float* ws) {
    if (threadIdx.x < 2) ws[threadIdx.x] = 0.f;   // zeroes sum (f32) and count (i32)
}

extern "C" void kernel_launch(void* const* d_in, const int* in_sizes, int n_in,
                              void* d_out, int out_size, void* d_ws, size_t ws_size,
                              hipStream_t stream) {
    const float* inp = (const float*)d_in[0];
    const float* tgt = (const float*)d_in[1];
    float* ws  = (float*)d_ws;
    float* out = (float*)d_out;

    zero_kernel<<<1, 64, 0, stream>>>(ws);
    jitter_kernel<<<NBLOCKS, THREADS, 0, stream>>>(inp, tgt, ws, out);
}